// Round 1
// baseline (2375.519 us; speedup 1.0000x reference)
//
#include <hip/hip_runtime.h>

#define BB 4
#define NN 120000
#define FEAT 128
#define HH 128
#define WW 128
#define NPTS (BB*NN)
#define HW (HH*WW)

// ws float layout
#define OFF_W1 0        // 64x4
#define OFF_B1 256      // 64
#define OFF_W2 320      // [i=64][o=128] transposed: 8192
#define OFF_B2 8512     // 128
#define OFF_W3 8640     // [o/4=32][i=128][4]: 16384 (interleaved groups of 4 outputs)
#define OFF_B3 25024    // 128
#define OFF_BEV 25600   // aligned; 4*128*128*128 = 8388608 floats
#define BEV_ELEMS (BB*HW*FEAT)

__global__ void fold_weights_k(
    const float* __restrict__ W1, const float* __restrict__ b1,
    const float* __restrict__ g1, const float* __restrict__ be1,
    const float* __restrict__ m1, const float* __restrict__ v1,
    const float* __restrict__ W2, const float* __restrict__ b2,
    const float* __restrict__ g2, const float* __restrict__ be2,
    const float* __restrict__ m2, const float* __restrict__ v2,
    const float* __restrict__ W3, const float* __restrict__ b3,
    const float* __restrict__ g3, const float* __restrict__ be3,
    const float* __restrict__ m3, const float* __restrict__ v3,
    float* __restrict__ wf)
{
    int idx = blockIdx.x * 256 + threadIdx.x;
    const float EPSV = 1e-5f;
    if (idx < 256) {                       // W1f [o=64][i=4]
        int o = idx >> 2;
        float s = g1[o] * rsqrtf(v1[o] + EPSV);
        wf[OFF_W1 + idx] = W1[idx] * s;
    } else if (idx < 320) {                // b1f
        int o = idx - 256;
        float s = g1[o] * rsqrtf(v1[o] + EPSV);
        wf[idx] = (b1[o] - m1[o]) * s + be1[o];
    } else if (idx < 8512) {               // W2f_t [i=64][o=128]
        int j = idx - OFF_W2;
        int i = j >> 7, o = j & 127;
        float s = g2[o] * rsqrtf(v2[o] + EPSV);
        wf[idx] = W2[o * 64 + i] * s;
    } else if (idx < 8640) {               // b2f
        int o = idx - OFF_B2;
        float s = g2[o] * rsqrtf(v2[o] + EPSV);
        wf[idx] = (b2[o] - m2[o]) * s + be2[o];
    } else if (idx < 25024) {              // W3f interleaved [oq=32][i=128][ol=4]
        int j = idx - OFF_W3;
        int oq = j >> 9;
        int r = j & 511;
        int i = r >> 2, ol = r & 3;
        int o = oq * 4 + ol;
        float s = g3[o] * rsqrtf(v3[o] + EPSV);
        wf[idx] = W3[o * 128 + i] * s;
    } else if (idx < 25152) {              // b3f
        int o = idx - OFF_B3;
        float s = g3[o] * rsqrtf(v3[o] + EPSV);
        wf[idx] = (b3[o] - m3[o]) * s + be3[o];
    }
}

// layout 0: bev[(b*HW+cell)*128 + o]  (feature-contiguous ws, transposed later)
// layout 1: bev[(b*128+o)*HW + cell]  (direct into d_out)
__global__ __launch_bounds__(256, 2)
void mlp_scatter_k(const float4* __restrict__ pts, const float* __restrict__ wf,
                   float* __restrict__ bev, int layout)
{
    __shared__ float h1s[64 * 256];
    const int tid = threadIdx.x;
    const int idx = blockIdx.x * 256 + tid;

    float4 p = pts[idx];

    // grid cell (mirror reference math exactly)
    float xn = (p.x - (-50.0f)) / (50.0f - (-50.0f));
    float yn = (p.y - (-50.0f)) / (50.0f - (-50.0f));
    bool valid = (xn >= 0.0f) && (xn <= 1.0f) && (yn >= 0.0f) && (yn <= 1.0f);
    int gx = (int)(xn * 127.0f); gx = min(max(gx, 0), 127);
    int gy = (int)(yn * 127.0f); gy = min(max(gy, 0), 127);
    int b = idx / NN;
    int cell = gy * WW + gx;

    // ---- layer 1: 4 -> 64 (weights scalar-loaded; fully unrolled) ----
    float h1[64];
#pragma unroll
    for (int o = 0; o < 64; ++o) {
        float a = wf[OFF_B1 + o];
        a = fmaf(wf[OFF_W1 + o * 4 + 0], p.x, a);
        a = fmaf(wf[OFF_W1 + o * 4 + 1], p.y, a);
        a = fmaf(wf[OFF_W1 + o * 4 + 2], p.z, a);
        a = fmaf(wf[OFF_W1 + o * 4 + 3], p.w, a);
        h1[o] = fmaxf(a, 0.0f);
    }
    // stash h1 in LDS (lane-contiguous rows -> conflict-free; same-thread RAW, no barrier)
#pragma unroll
    for (int o = 0; o < 64; ++o) h1s[o * 256 + tid] = h1[o];

    // ---- layer 2: 64 -> 128, dynamic i, 128 independent accumulators ----
    float h2[128];
#pragma unroll
    for (int o = 0; o < 128; ++o) h2[o] = wf[OFF_B2 + o];
#pragma unroll 2
    for (int i = 0; i < 64; ++i) {
        float v = h1s[i * 256 + tid];
        const float* wrow = wf + OFF_W2 + i * 128;
#pragma unroll
        for (int o = 0; o < 128; ++o) h2[o] = fmaf(wrow[o], v, h2[o]);
    }
#pragma unroll
    for (int o = 0; o < 128; ++o) h2[o] = fmaxf(h2[o], 0.0f);

    // ---- layer 3: 128 -> 128, dynamic o (x4 accs), unrolled i over reg h2 ----
#pragma unroll 1
    for (int o = 0; o < 128; o += 4) {
        float a0 = wf[OFF_B3 + o + 0];
        float a1 = wf[OFF_B3 + o + 1];
        float a2 = wf[OFF_B3 + o + 2];
        float a3 = wf[OFF_B3 + o + 3];
        const float* wq = wf + OFF_W3 + (o >> 2) * 512;   // [i][4] interleaved
#pragma unroll
        for (int i = 0; i < 128; ++i) {
            float v = h2[i];
            a0 = fmaf(wq[i * 4 + 0], v, a0);
            a1 = fmaf(wq[i * 4 + 1], v, a1);
            a2 = fmaf(wq[i * 4 + 2], v, a2);
            a3 = fmaf(wq[i * 4 + 3], v, a3);
        }
        if (valid) {
            a0 = fmaxf(a0, 0.0f); a1 = fmaxf(a1, 0.0f);
            a2 = fmaxf(a2, 0.0f); a3 = fmaxf(a3, 0.0f);
            // post-ReLU values >= 0: int-bit atomicMax == float max vs 0-init
            int* ob = (int*)bev;
            if (layout == 0) {
                int base = (b * HW + cell) * 128 + o;
                atomicMax(ob + base + 0, __float_as_int(a0));
                atomicMax(ob + base + 1, __float_as_int(a1));
                atomicMax(ob + base + 2, __float_as_int(a2));
                atomicMax(ob + base + 3, __float_as_int(a3));
            } else {
                int base = b * 128 * HW + cell;
                atomicMax(ob + base + (o + 0) * HW, __float_as_int(a0));
                atomicMax(ob + base + (o + 1) * HW, __float_as_int(a1));
                atomicMax(ob + base + (o + 2) * HW, __float_as_int(a2));
                atomicMax(ob + base + (o + 3) * HW, __float_as_int(a3));
            }
        }
    }
}

// (B*HW, 128) -> (B, 128, HW) via 32x128 LDS tiles
__global__ void transpose_bev_k(const float* __restrict__ bev, float* __restrict__ out)
{
    __shared__ float tile[32][129];
    const int tid = threadIdx.x;
    const int cell0 = blockIdx.x * 32;          // global cell, 32 | HW so b uniform
#pragma unroll
    for (int k = 0; k < 16; ++k) {
        int idx = k * 256 + tid;
        int c = idx >> 7, f = idx & 127;
        tile[c][f] = bev[(size_t)(cell0 + c) * 128 + f];
    }
    __syncthreads();
    const int b = cell0 >> 14;                  // /16384
    const int cl0 = cell0 & (HW - 1);
#pragma unroll
    for (int k = 0; k < 16; ++k) {
        int idx = k * 256 + tid;
        int f = idx >> 5, c = idx & 31;
        out[(size_t)(b * 128 + f) * HW + cl0 + c] = tile[c][f];
    }
}

extern "C" void kernel_launch(void* const* d_in, const int* in_sizes, int n_in,
                              void* d_out, int out_size, void* d_ws, size_t ws_size,
                              hipStream_t stream)
{
    const float* points = (const float*)d_in[0];
    const float* W1 = (const float*)d_in[1];  const float* b1 = (const float*)d_in[2];
    const float* g1 = (const float*)d_in[3];  const float* be1 = (const float*)d_in[4];
    const float* m1 = (const float*)d_in[5];  const float* v1 = (const float*)d_in[6];
    const float* W2 = (const float*)d_in[7];  const float* b2 = (const float*)d_in[8];
    const float* g2 = (const float*)d_in[9];  const float* be2 = (const float*)d_in[10];
    const float* m2 = (const float*)d_in[11]; const float* v2 = (const float*)d_in[12];
    const float* W3 = (const float*)d_in[13]; const float* b3 = (const float*)d_in[14];
    const float* g3 = (const float*)d_in[15]; const float* be3 = (const float*)d_in[16];
    const float* m3 = (const float*)d_in[17]; const float* v3 = (const float*)d_in[18];

    float* wsf = (float*)d_ws;
    const size_t need = (size_t)(OFF_BEV + BEV_ELEMS) * sizeof(float);
    const int layout = (ws_size >= need) ? 0 : 1;

    fold_weights_k<<<(25152 + 255) / 256, 256, 0, stream>>>(
        W1, b1, g1, be1, m1, v1, W2, b2, g2, be2, m2, v2, W3, b3, g3, be3, m3, v3, wsf);

    float* bev;
    if (layout == 0) {
        bev = wsf + OFF_BEV;
        hipMemsetAsync(bev, 0, (size_t)BEV_ELEMS * sizeof(float), stream);
    } else {
        bev = (float*)d_out;
        hipMemsetAsync(d_out, 0, (size_t)out_size * sizeof(float), stream);
    }

    mlp_scatter_k<<<NPTS / 256, 256, 0, stream>>>(
        (const float4*)points, wsf, bev, layout);

    if (layout == 0) {
        transpose_bev_k<<<HW * BB / 32, 256, 0, stream>>>(bev, (float*)d_out);
    }
}

// Round 2
// 727.885 us; speedup vs baseline: 3.2636x; 3.2636x over previous
//
#include <hip/hip_runtime.h>
#include <hip/hip_fp16.h>

#define BB 4
#define NN 120000
#define FEAT 128
#define HH 128
#define WW 128
#define NPTS (BB*NN)
#define HW (HH*WW)

// ---- ws layout (4-byte element offsets) ----
#define OFF_W1 0        // 64x4 f32
#define OFF_B1 256      // 64
#define OFF_W2 320      // [i=64][o=128] f32
#define OFF_B2 8512     // 128
#define OFF_W3 8640     // [oq=32][i=128][4] f32
#define OFF_B3 25024    // 128
#define CNT_OFF   25152             // int[65536]
#define OFFS_OFF  (CNT_OFF+65536)   // int[65536]
#define NV_OFF    (OFFS_OFF+65536)  // int[1]
#define CELLS_OFF (NV_OFF+4)        // int[NPTS]
#define SIDX_OFF  (CELLS_OFF+NPTS)  // int[NPTS]
#define SCELL_OFF (SIDX_OFF+NPTS)   // int[NPTS]
#define END_B     (SCELL_OFF+NPTS)  // = 1596232
#define BEV_OFF   1596416           // f32[BB*HW*128]
#define BEV_ELEMS (BB*HW*FEAT)

__global__ void fold_weights_k(
    const float* __restrict__ W1, const float* __restrict__ b1,
    const float* __restrict__ g1, const float* __restrict__ be1,
    const float* __restrict__ m1, const float* __restrict__ v1,
    const float* __restrict__ W2, const float* __restrict__ b2,
    const float* __restrict__ g2, const float* __restrict__ be2,
    const float* __restrict__ m2, const float* __restrict__ v2,
    const float* __restrict__ W3, const float* __restrict__ b3,
    const float* __restrict__ g3, const float* __restrict__ be3,
    const float* __restrict__ m3, const float* __restrict__ v3,
    float* __restrict__ wf)
{
    int idx = blockIdx.x * 256 + threadIdx.x;
    const float EPSV = 1e-5f;
    if (idx < 256) {
        int o = idx >> 2;
        float s = g1[o] * rsqrtf(v1[o] + EPSV);
        wf[OFF_W1 + idx] = W1[idx] * s;
    } else if (idx < 320) {
        int o = idx - 256;
        float s = g1[o] * rsqrtf(v1[o] + EPSV);
        wf[idx] = (b1[o] - m1[o]) * s + be1[o];
    } else if (idx < 8512) {
        int j = idx - OFF_W2;
        int i = j >> 7, o = j & 127;
        float s = g2[o] * rsqrtf(v2[o] + EPSV);
        wf[idx] = W2[o * 64 + i] * s;
    } else if (idx < 8640) {
        int o = idx - OFF_B2;
        float s = g2[o] * rsqrtf(v2[o] + EPSV);
        wf[idx] = (b2[o] - m2[o]) * s + be2[o];
    } else if (idx < 25024) {
        int j = idx - OFF_W3;
        int oq = j >> 9;
        int r = j & 511;
        int i = r >> 2, ol = r & 3;
        int o = oq * 4 + ol;
        float s = g3[o] * rsqrtf(v3[o] + EPSV);
        wf[idx] = W3[o * 128 + i] * s;
    } else if (idx < 25152) {
        int o = idx - OFF_B3;
        float s = g3[o] * rsqrtf(v3[o] + EPSV);
        wf[idx] = (b3[o] - m3[o]) * s + be3[o];
    }
}

// ---- pass 1: cell id per point + histogram ----
__global__ __launch_bounds__(256)
void cells_hist_k(const float4* __restrict__ pts, int* __restrict__ cells,
                  int* __restrict__ cnt)
{
    int tid = blockIdx.x * 256 + threadIdx.x;
    float4 p = pts[tid];
    float xn = (p.x - (-50.0f)) / (50.0f - (-50.0f));
    float yn = (p.y - (-50.0f)) / (50.0f - (-50.0f));
    bool valid = (xn >= 0.0f) && (xn <= 1.0f) && (yn >= 0.0f) && (yn <= 1.0f);
    int gx = min(max((int)(xn * 127.0f), 0), 127);
    int gy = min(max((int)(yn * 127.0f), 0), 127);
    int b = tid / NN;
    int cell = valid ? (b * HW + gy * WW + gx) : -1;
    cells[tid] = cell;
    if (valid) atomicAdd(&cnt[cell], 1);
}

// ---- pass 2: exclusive prefix scan of 65536 bins (single block) ----
__global__ __launch_bounds__(1024)
void scan_k(const int* __restrict__ cnt, int* __restrict__ off, int* __restrict__ nvp)
{
    __shared__ int wsum[16];
    int t = threadIdx.x;
    int lane = t & 63, w = t >> 6;
    int base = t * 64;
    int s = 0;
#pragma unroll 8
    for (int j = 0; j < 64; ++j) s += cnt[base + j];
    // wave inclusive scan of per-thread sums
    int v = s;
#pragma unroll
    for (int d = 1; d < 64; d <<= 1) {
        int u = __shfl_up(v, d);
        if (lane >= d) v += u;
    }
    if (lane == 63) wsum[w] = v;
    __syncthreads();
    if (t == 0) {
        int r = 0;
#pragma unroll
        for (int k = 0; k < 16; ++k) { int x = wsum[k]; wsum[k] = r; r += x; }
        nvp[0] = r;
    }
    __syncthreads();
    int excl = (v - s) + wsum[w];
    int r = excl;
#pragma unroll 8
    for (int j = 0; j < 64; ++j) { off[base + j] = r; r += cnt[base + j]; }
}

// ---- pass 3: scatter point indices into sorted order ----
__global__ __launch_bounds__(256)
void scatter_idx_k(const int* __restrict__ cells, int* __restrict__ off,
                   int* __restrict__ sidx, int* __restrict__ scell)
{
    int tid = blockIdx.x * 256 + threadIdx.x;
    int c = cells[tid];
    if (c >= 0) {
        int pos = atomicAdd(&off[c], 1);
        sidx[pos] = tid;
        scell[pos] = c;
    }
}

// DPP row_shr:<d> guarded max-merge (segmented scan step within 16-lane rows)
#define DPPMAX(A, D, S) { \
    float _pv = __int_as_float(__builtin_amdgcn_update_dpp( \
        0, __float_as_int(A), 0x110 | (D), 0xF, 0xF, false)); \
    A = (S) ? fmaxf(A, _pv) : A; }

// ---- pass 4: MLP over sorted points + run-merged scatter-max ----
// layout 0: bev[cell*128 + o] (ws, transposed later); layout 1: out[(b*128+o)*HW + cxy]
__global__ __launch_bounds__(256)
void mlp_sorted_k(const float4* __restrict__ pts, const float* __restrict__ wf,
                  const int* __restrict__ sidx, const int* __restrict__ scell,
                  const int* __restrict__ nvp, float* __restrict__ bev, int layout)
{
    __shared__ __half2 h2s[64 * 256];   // 64 KB: packed h2 pairs, per-thread column
    const int tid = threadIdx.x;
    const int slot = blockIdx.x * 256 + tid;
    const int nv = nvp[0];
    if ((slot & ~63) >= nv) return;     // whole-wave uniform exit
    const int lane = tid & 63;
    const int l15 = lane & 15;
    const bool live = slot < nv;
    const int cell = live ? scell[slot] : -1;
    const int pidx = live ? sidx[slot] : 0;
    float4 p = pts[pidx];

    // neighbor-cell masks for the segmented max (runs are contiguous after sort)
    int c1 = __shfl_up(cell, 1), c2 = __shfl_up(cell, 2);
    int c4 = __shfl_up(cell, 4), c8 = __shfl_up(cell, 8);
    bool s1 = (l15 >= 1) && (c1 == cell);
    bool s2 = (l15 >= 2) && (c2 == cell);
    bool s4 = (l15 >= 4) && (c4 == cell);
    bool s8 = (l15 >= 8) && (c8 == cell);
    int cn = __shfl_down(cell, 1);
    bool tail = (l15 == 15) || (cn != cell);

    // ---- layer 1: 4 -> 64, h1 in registers (s_load weights) ----
    float h1[64];
#pragma unroll
    for (int o = 0; o < 64; ++o) {
        float a = wf[OFF_B1 + o];
        a = fmaf(wf[OFF_W1 + o * 4 + 0], p.x, a);
        a = fmaf(wf[OFF_W1 + o * 4 + 1], p.y, a);
        a = fmaf(wf[OFF_W1 + o * 4 + 2], p.z, a);
        a = fmaf(wf[OFF_W1 + o * 4 + 3], p.w, a);
        h1[o] = fmaxf(a, 0.0f);
    }

    // ---- layer 2: 64 -> 128 in 8 chunks of 16 accs; pack fp16 pairs to LDS ----
#pragma unroll 1
    for (int o0 = 0; o0 < 128; o0 += 16) {
        float acc[16];
#pragma unroll
        for (int j = 0; j < 16; ++j) acc[j] = wf[OFF_B2 + o0 + j];
#pragma unroll
        for (int i = 0; i < 64; ++i) {
            float v = h1[i];
            const float* wr = wf + OFF_W2 + i * 128 + o0;
#pragma unroll
            for (int j = 0; j < 16; ++j) acc[j] = fmaf(wr[j], v, acc[j]);
        }
#pragma unroll
        for (int j = 0; j < 16; j += 2) {
            h2s[((o0 + j) >> 1) * 256 + tid] =
                __floats2half2_rn(fmaxf(acc[j], 0.0f), fmaxf(acc[j + 1], 0.0f));
        }
    }

    // ---- layer 3: 128 -> 128 in 16 chunks of 8; fused run-max + atomic ----
    int* ob = (int*)bev;
    long base0;
    if (layout == 0) base0 = (long)cell * 128;
    else             base0 = (long)(cell >> 14) * (128 * HW) + (cell & (HW - 1));

#pragma unroll 1
    for (int o0 = 0; o0 < 128; o0 += 8) {
        float a[8];
#pragma unroll
        for (int j = 0; j < 8; ++j) a[j] = wf[OFF_B3 + o0 + j];
        const float* wqA = wf + OFF_W3 + (o0 >> 2) * 512;
        const float* wqB = wqA + 512;
#pragma unroll
        for (int r = 0; r < 64; ++r) {
            __half2 hp = h2s[r * 256 + tid];
            float lo = __low2float(hp), hi = __high2float(hp);
#pragma unroll
            for (int j = 0; j < 4; ++j) {
                a[j]     = fmaf(wqA[(2 * r) * 4 + j], lo, a[j]);
                a[j]     = fmaf(wqA[(2 * r + 1) * 4 + j], hi, a[j]);
                a[4 + j] = fmaf(wqB[(2 * r) * 4 + j], lo, a[4 + j]);
                a[4 + j] = fmaf(wqB[(2 * r + 1) * 4 + j], hi, a[4 + j]);
            }
        }
#pragma unroll
        for (int j = 0; j < 8; ++j) {
            a[j] = fmaxf(a[j], 0.0f);
            DPPMAX(a[j], 1, s1); DPPMAX(a[j], 2, s2);
            DPPMAX(a[j], 4, s4); DPPMAX(a[j], 8, s8);
        }
        if (tail && cell >= 0) {
            if (layout == 0) {
#pragma unroll
                for (int j = 0; j < 8; ++j)
                    atomicMax(ob + base0 + o0 + j, __float_as_int(a[j]));
            } else {
#pragma unroll
                for (int j = 0; j < 8; ++j)
                    atomicMax(ob + base0 + (long)(o0 + j) * HW, __float_as_int(a[j]));
            }
        }
    }
}

// (B*HW, 128) -> (B, 128, HW)
__global__ void transpose_bev_k(const float* __restrict__ bev, float* __restrict__ out)
{
    __shared__ float tile[32][129];
    const int tid = threadIdx.x;
    const int cell0 = blockIdx.x * 32;
#pragma unroll
    for (int k = 0; k < 16; ++k) {
        int idx = k * 256 + tid;
        int c = idx >> 7, f = idx & 127;
        tile[c][f] = bev[(size_t)(cell0 + c) * 128 + f];
    }
    __syncthreads();
    const int b = cell0 >> 14;
    const int cl0 = cell0 & (HW - 1);
#pragma unroll
    for (int k = 0; k < 16; ++k) {
        int idx = k * 256 + tid;
        int f = idx >> 5, c = idx & 31;
        out[(size_t)(b * 128 + f) * HW + cl0 + c] = tile[c][f];
    }
}

// ---- mode C fallback (tiny ws): round-1-style direct atomic kernel ----
__global__ __launch_bounds__(256)
void mlp_scatter_fallback_k(const float4* __restrict__ pts, const float* __restrict__ wf,
                            float* __restrict__ bev)
{
    __shared__ float h1s[64 * 256];
    const int tid = threadIdx.x;
    const int idx = blockIdx.x * 256 + tid;
    float4 p = pts[idx];
    float xn = (p.x - (-50.0f)) / (50.0f - (-50.0f));
    float yn = (p.y - (-50.0f)) / (50.0f - (-50.0f));
    bool valid = (xn >= 0.0f) && (xn <= 1.0f) && (yn >= 0.0f) && (yn <= 1.0f);
    int gx = min(max((int)(xn * 127.0f), 0), 127);
    int gy = min(max((int)(yn * 127.0f), 0), 127);
    int b = idx / NN;
    int cell = gy * WW + gx;
    float h1[64];
#pragma unroll
    for (int o = 0; o < 64; ++o) {
        float a = wf[OFF_B1 + o];
        a = fmaf(wf[OFF_W1 + o * 4 + 0], p.x, a);
        a = fmaf(wf[OFF_W1 + o * 4 + 1], p.y, a);
        a = fmaf(wf[OFF_W1 + o * 4 + 2], p.z, a);
        a = fmaf(wf[OFF_W1 + o * 4 + 3], p.w, a);
        h1[o] = fmaxf(a, 0.0f);
    }
#pragma unroll
    for (int o = 0; o < 64; ++o) h1s[o * 256 + tid] = h1[o];
    int* ob = (int*)bev;
    long basec = (long)b * 128 * HW + cell;
#pragma unroll 1
    for (int o0 = 0; o0 < 128; o0 += 16) {   // layer2 chunk
        float acc[16];
#pragma unroll
        for (int j = 0; j < 16; ++j) acc[j] = wf[OFF_B2 + o0 + j];
#pragma unroll 4
        for (int i = 0; i < 64; ++i) {
            float v = h1s[i * 256 + tid];
            const float* wr = wf + OFF_W2 + i * 128 + o0;
#pragma unroll
            for (int j = 0; j < 16; ++j) acc[j] = fmaf(wr[j], v, acc[j]);
        }
#pragma unroll
        for (int j = 0; j < 16; ++j) h1s[0 * 0] = h1s[0 * 0]; // no-op keep simple
        // store h2 chunk into registers-in-LDS? fallback: reuse h1s rows above 64? not enough.
        // Simple: keep h2 chunk in LDS rows (o0/16 uses 16 rows of a second region) --
        // fallback mode is correctness-only; stash to global-free path: recompute below.
#pragma unroll
        for (int j = 0; j < 16; ++j) acc[j] = fmaxf(acc[j], 0.0f);
        // write chunk to LDS rows [o0..o0+15] of a 2nd buffer region is too big;
        // instead: directly accumulate partial layer-3 contributions via atomics is wrong.
        // So fallback does layer3 with on-the-fly h2 chunk accumulation:
        // handled outside (see below) -- store chunk to h1s rows is impossible, so
        // we instead fold layer 3 here: for each chunk, accumulate into out via atomicAdd? invalid.
        // => fallback recomputes h2 per layer-3 chunk (slow but correct):
        (void)acc;
    }
    // correctness-only path: full recompute per output chunk (slow, only if ws tiny)
#pragma unroll 1
    for (int o = 0; o < 128; o += 4) {
        float a0 = wf[OFF_B3 + o + 0], a1 = wf[OFF_B3 + o + 1];
        float a2 = wf[OFF_B3 + o + 2], a3 = wf[OFF_B3 + o + 3];
        const float* wq = wf + OFF_W3 + (o >> 2) * 512;
#pragma unroll 1
        for (int i0 = 0; i0 < 128; i0 += 16) {
            float h2c[16];
#pragma unroll
            for (int j = 0; j < 16; ++j) h2c[j] = wf[OFF_B2 + i0 + j];
#pragma unroll 4
            for (int i = 0; i < 64; ++i) {
                float v = h1s[i * 256 + tid];
                const float* wr = wf + OFF_W2 + i * 128 + i0;
#pragma unroll
                for (int j = 0; j < 16; ++j) h2c[j] = fmaf(wr[j], v, h2c[j]);
            }
#pragma unroll
            for (int j = 0; j < 16; ++j) {
                float v = fmaxf(h2c[j], 0.0f);
                a0 = fmaf(wq[(i0 + j) * 4 + 0], v, a0);
                a1 = fmaf(wq[(i0 + j) * 4 + 1], v, a1);
                a2 = fmaf(wq[(i0 + j) * 4 + 2], v, a2);
                a3 = fmaf(wq[(i0 + j) * 4 + 3], v, a3);
            }
        }
        if (valid) {
            atomicMax(ob + basec + (long)(o + 0) * HW, __float_as_int(fmaxf(a0, 0.0f)));
            atomicMax(ob + basec + (long)(o + 1) * HW, __float_as_int(fmaxf(a1, 0.0f)));
            atomicMax(ob + basec + (long)(o + 2) * HW, __float_as_int(fmaxf(a2, 0.0f)));
            atomicMax(ob + basec + (long)(o + 3) * HW, __float_as_int(fmaxf(a3, 0.0f)));
        }
    }
}

extern "C" void kernel_launch(void* const* d_in, const int* in_sizes, int n_in,
                              void* d_out, int out_size, void* d_ws, size_t ws_size,
                              hipStream_t stream)
{
    const float* points = (const float*)d_in[0];
    const float* W1 = (const float*)d_in[1];  const float* b1 = (const float*)d_in[2];
    const float* g1 = (const float*)d_in[3];  const float* be1 = (const float*)d_in[4];
    const float* m1 = (const float*)d_in[5];  const float* v1 = (const float*)d_in[6];
    const float* W2 = (const float*)d_in[7];  const float* b2 = (const float*)d_in[8];
    const float* g2 = (const float*)d_in[9];  const float* be2 = (const float*)d_in[10];
    const float* m2 = (const float*)d_in[11]; const float* v2 = (const float*)d_in[12];
    const float* W3 = (const float*)d_in[13]; const float* b3 = (const float*)d_in[14];
    const float* g3 = (const float*)d_in[15]; const float* be3 = (const float*)d_in[16];
    const float* m3 = (const float*)d_in[17]; const float* v3 = (const float*)d_in[18];

    float* wsf = (float*)d_ws;
    int*   wsi = (int*)d_ws;
    const size_t need_A = (size_t)(BEV_OFF + BEV_ELEMS) * 4;
    const size_t need_B = (size_t)END_B * 4;

    fold_weights_k<<<(25152 + 255) / 256, 256, 0, stream>>>(
        W1, b1, g1, be1, m1, v1, W2, b2, g2, be2, m2, v2, W3, b3, g3, be3, m3, v3, wsf);

    if (ws_size >= need_B) {
        // sort-by-cell pipeline
        hipMemsetAsync(wsi + CNT_OFF, 0, 65536 * sizeof(int), stream);
        cells_hist_k<<<NPTS / 256, 256, 0, stream>>>(
            (const float4*)points, wsi + CELLS_OFF, wsi + CNT_OFF);
        scan_k<<<1, 1024, 0, stream>>>(wsi + CNT_OFF, wsi + OFFS_OFF, wsi + NV_OFF);
        scatter_idx_k<<<NPTS / 256, 256, 0, stream>>>(
            wsi + CELLS_OFF, wsi + OFFS_OFF, wsi + SIDX_OFF, wsi + SCELL_OFF);

        if (ws_size >= need_A) {
            float* bev = wsf + BEV_OFF;
            hipMemsetAsync(bev, 0, (size_t)BEV_ELEMS * sizeof(float), stream);
            mlp_sorted_k<<<NPTS / 256, 256, 0, stream>>>(
                (const float4*)points, wsf, wsi + SIDX_OFF, wsi + SCELL_OFF,
                wsi + NV_OFF, bev, 0);
            transpose_bev_k<<<HW * BB / 32, 256, 0, stream>>>(bev, (float*)d_out);
        } else {
            hipMemsetAsync(d_out, 0, (size_t)out_size * sizeof(float), stream);
            mlp_sorted_k<<<NPTS / 256, 256, 0, stream>>>(
                (const float4*)points, wsf, wsi + SIDX_OFF, wsi + SCELL_OFF,
                wsi + NV_OFF, (float*)d_out, 1);
        }
    } else {
        // tiny-ws fallback: direct atomics (correctness-only)
        hipMemsetAsync(d_out, 0, (size_t)out_size * sizeof(float), stream);
        mlp_scatter_fallback_k<<<NPTS / 256, 256, 0, stream>>>(
            (const float4*)points, wsf, (float*)d_out);
    }
}

// Round 3
// 418.947 us; speedup vs baseline: 5.6702x; 1.7374x over previous
//
#include <hip/hip_runtime.h>
#include <hip/hip_fp16.h>

#define BB 4
#define NN 120000
#define FEAT 128
#define HH 128
#define WW 128
#define NPTS (BB*NN)
#define HW (HH*WW)

// ---- ws layout (4-byte element offsets) ----
#define OW1    0         // f32[256]  [o=64][i=4]
#define OB1    256       // f32[64]
#define OW2P   320       // u32[4096] packed half2 [r=32][o=128], pair r = inputs (2r,2r+1)
#define OB2    4416      // f32[128]
#define OW3P   4544      // u32[8192] packed half2 [chunk=16][r=64][j=8], o = chunk*8+j
#define OB3    12736     // f32[128]
#define OCNT   12864     // i32[65536]
#define OOFF   78400     // i32[65536]
#define ONV    143936    // i32[1] (padded to 64)
#define OCELLS 144000    // i32[NPTS]
#define OSIDX  624000    // i32[NPTS]
#define OSCELL 1104000   // i32[NPTS]
#define OENDB  1584000
#define OBEV   1584000   // B path layout0: f32[BB*HW*128]
#define OFEATS 1584000   // A path: u32[NPTS*64] (full) or u32[NPTS*32] (half)
#define BEV_ELEMS (BB*HW*FEAT)

#if defined(__has_builtin)
#if __has_builtin(__builtin_amdgcn_fdot2)
#define HAS_FDOT2 1
#endif
#endif

typedef _Float16 hv2 __attribute__((ext_vector_type(2)));

__device__ __forceinline__ unsigned pk2(float a, float b) {
    __half2 h = __floats2half2_rn(a, b);
    return __builtin_bit_cast(unsigned, h);
}

__device__ __forceinline__ float dot2(unsigned a, unsigned b, float c) {
#ifdef HAS_FDOT2
    return __builtin_amdgcn_fdot2(__builtin_bit_cast(hv2, a),
                                  __builtin_bit_cast(hv2, b), c, false);
#else
    __half2 ah = __builtin_bit_cast(__half2, a), bh = __builtin_bit_cast(__half2, b);
    c = fmaf(__low2float(ah), __low2float(bh), c);
    return fmaf(__high2float(ah), __high2float(bh), c);
#endif
}

// ---------------- weight folding + fp16 packing ----------------
__global__ void fold_weights_k(
    const float* __restrict__ W1, const float* __restrict__ b1,
    const float* __restrict__ g1, const float* __restrict__ be1,
    const float* __restrict__ m1, const float* __restrict__ v1,
    const float* __restrict__ W2, const float* __restrict__ b2,
    const float* __restrict__ g2, const float* __restrict__ be2,
    const float* __restrict__ m2, const float* __restrict__ v2,
    const float* __restrict__ W3, const float* __restrict__ b3,
    const float* __restrict__ g3, const float* __restrict__ be3,
    const float* __restrict__ m3, const float* __restrict__ v3,
    float* __restrict__ wf)
{
    unsigned* wu = (unsigned*)wf;
    int idx = blockIdx.x * 256 + threadIdx.x;
    const float EPSV = 1e-5f;
    if (idx < 256) {                         // W1f
        int o = idx >> 2;
        float s = g1[o] * rsqrtf(v1[o] + EPSV);
        wf[OW1 + idx] = W1[idx] * s;
    } else if (idx < 320) {                  // b1f
        int o = idx - 256;
        float s = g1[o] * rsqrtf(v1[o] + EPSV);
        wf[idx] = (b1[o] - m1[o]) * s + be1[o];
    } else if (idx < 4416) {                 // W2 packed
        int j = idx - OW2P;
        int r = j >> 7, o = j & 127;
        float s = g2[o] * rsqrtf(v2[o] + EPSV);
        wu[idx] = pk2(W2[o * 64 + 2 * r] * s, W2[o * 64 + 2 * r + 1] * s);
    } else if (idx < 4544) {                 // b2f
        int o = idx - OB2;
        float s = g2[o] * rsqrtf(v2[o] + EPSV);
        wf[idx] = (b2[o] - m2[o]) * s + be2[o];
    } else if (idx < 12736) {                // W3 packed
        int j = idx - OW3P;
        int ch = j >> 9, rem = j & 511;
        int r = rem >> 3, jj = rem & 7;
        int o = ch * 8 + jj;
        float s = g3[o] * rsqrtf(v3[o] + EPSV);
        wu[idx] = pk2(W3[o * 128 + 2 * r] * s, W3[o * 128 + 2 * r + 1] * s);
    } else if (idx < 12864) {                // b3f
        int o = idx - OB3;
        float s = g3[o] * rsqrtf(v3[o] + EPSV);
        wf[idx] = (b3[o] - m3[o]) * s + be3[o];
    }
}

// ---------------- sort-by-cell passes ----------------
__global__ __launch_bounds__(256)
void cells_hist_k(const float4* __restrict__ pts, int* __restrict__ cells,
                  int* __restrict__ cnt)
{
    int tid = blockIdx.x * 256 + threadIdx.x;
    float4 p = pts[tid];
    float xn = (p.x - (-50.0f)) / (50.0f - (-50.0f));
    float yn = (p.y - (-50.0f)) / (50.0f - (-50.0f));
    bool valid = (xn >= 0.0f) && (xn <= 1.0f) && (yn >= 0.0f) && (yn <= 1.0f);
    int gx = min(max((int)(xn * 127.0f), 0), 127);
    int gy = min(max((int)(yn * 127.0f), 0), 127);
    int b = tid / NN;
    int cell = valid ? (b * HW + gy * WW + gx) : -1;
    cells[tid] = cell;
    if (valid) atomicAdd(&cnt[cell], 1);
}

__global__ __launch_bounds__(1024)
void scan_k(const int* __restrict__ cnt, int* __restrict__ off, int* __restrict__ nvp)
{
    __shared__ int wsum[16];
    int t = threadIdx.x;
    int lane = t & 63, w = t >> 6;
    int base = t * 64;
    int s = 0;
#pragma unroll 8
    for (int j = 0; j < 64; ++j) s += cnt[base + j];
    int v = s;
#pragma unroll
    for (int d = 1; d < 64; d <<= 1) {
        int u = __shfl_up(v, d);
        if (lane >= d) v += u;
    }
    if (lane == 63) wsum[w] = v;
    __syncthreads();
    if (t == 0) {
        int r = 0;
#pragma unroll
        for (int k = 0; k < 16; ++k) { int x = wsum[k]; wsum[k] = r; r += x; }
        nvp[0] = r;
    }
    __syncthreads();
    int excl = (v - s) + wsum[w];
    int r = excl;
#pragma unroll 8
    for (int j = 0; j < 64; ++j) { off[base + j] = r; r += cnt[base + j]; }
}

__global__ __launch_bounds__(256)
void scatter_idx_k(const int* __restrict__ cells, int* __restrict__ off,
                   int* __restrict__ sidx, int* __restrict__ scell)
{
    int tid = blockIdx.x * 256 + threadIdx.x;
    int c = cells[tid];
    if (c >= 0) {
        int pos = atomicAdd(&off[c], 1);
        sidx[pos] = tid;
        scell[pos] = c;
    }
}

// ---------------- shared MLP device code ----------------
__device__ __forceinline__ void mlp12(const float4 p, const float* __restrict__ wf,
                                      const unsigned* __restrict__ wu,
                                      unsigned h2p[64])
{
    unsigned h1p[32];
#pragma unroll
    for (int i = 0; i < 32; ++i) {
        const float* wa = wf + OW1 + 8 * i;
        float a = wf[OB1 + 2 * i], b = wf[OB1 + 2 * i + 1];
        a = fmaf(wa[0], p.x, a); a = fmaf(wa[1], p.y, a);
        a = fmaf(wa[2], p.z, a); a = fmaf(wa[3], p.w, a);
        b = fmaf(wa[4], p.x, b); b = fmaf(wa[5], p.y, b);
        b = fmaf(wa[6], p.z, b); b = fmaf(wa[7], p.w, b);
        h1p[i] = pk2(fmaxf(a, 0.0f), fmaxf(b, 0.0f));
    }
#pragma unroll 1
    for (int o0 = 0; o0 < 128; o0 += 16) {
        float acc[16];
#pragma unroll
        for (int j = 0; j < 16; ++j) acc[j] = wf[OB2 + o0 + j];
#pragma unroll
        for (int r = 0; r < 32; ++r) {
            const unsigned* wr = wu + OW2P + r * 128 + o0;
#pragma unroll
            for (int j = 0; j < 16; ++j) acc[j] = dot2(h1p[r], wr[j], acc[j]);
        }
#pragma unroll
        for (int j = 0; j < 16; j += 2)
            h2p[(o0 + j) >> 1] = pk2(fmaxf(acc[j], 0.0f), fmaxf(acc[j + 1], 0.0f));
    }
}

__device__ __forceinline__ void l3chunk(int ch, const float* __restrict__ wf,
                                        const unsigned* __restrict__ wu,
                                        const unsigned h2p[64], float a[8])
{
#pragma unroll
    for (int j = 0; j < 8; ++j) a[j] = wf[OB3 + ch * 8 + j];
    const unsigned* wq = wu + OW3P + ch * 512;
#pragma unroll
    for (int r = 0; r < 64; ++r) {
#pragma unroll
        for (int j = 0; j < 8; ++j) a[j] = dot2(h2p[r], wq[r * 8 + j], a[j]);
    }
}

// ---------------- A path: MLP -> fp16 feats (no atomics, no LDS) ----------------
__global__ __launch_bounds__(256, 4)
void mlp_feats_k(const float4* __restrict__ pts, const float* __restrict__ wf,
                 const int* __restrict__ sidx, const int* __restrict__ nvp,
                 uint4* __restrict__ feats4, int cbegin, int ccount)
{
    const unsigned* wu = (const unsigned*)wf;
    const int slot = blockIdx.x * 256 + threadIdx.x;
    const int nv = nvp[0];
    if ((slot & ~63) >= nv) return;
    const bool live = slot < nv;
    const int pidx = live ? sidx[slot] : 0;
    float4 p = pts[pidx];

    unsigned h2p[64];
    mlp12(p, wf, wu, h2p);

#pragma unroll 1
    for (int c = cbegin; c < cbegin + ccount; ++c) {
        float a[8];
        l3chunk(c, wf, wu, h2p, a);
        if (live) {
            uint4 v;
            v.x = pk2(fmaxf(a[0], 0.0f), fmaxf(a[1], 0.0f));
            v.y = pk2(fmaxf(a[2], 0.0f), fmaxf(a[3], 0.0f));
            v.z = pk2(fmaxf(a[4], 0.0f), fmaxf(a[5], 0.0f));
            v.w = pk2(fmaxf(a[6], 0.0f), fmaxf(a[7], 0.0f));
            feats4[(size_t)slot * ccount + (c - cbegin)] = v;
        }
    }
}

// ---------------- A path: per-cell max-reduce, direct transposed output ----------------
__global__ __launch_bounds__(256)
void reduce_k(const unsigned* __restrict__ feats, const int* __restrict__ off,
              const int* __restrict__ cnt, float* __restrict__ out,
              int cbegin, int ccount)
{
    __shared__ float tile[128][65];
    const int tid = threadIdx.x;
    const int w = tid >> 6, l = tid & 63;
    const int c0 = blockIdx.x * 64;
    const int npair = 4 * ccount;           // uints per slot
    const bool lact = l < npair;

#pragma unroll 1
    for (int cc = 0; cc < 16; ++cc) {
        int c = c0 + w * 16 + cc;
        int n = cnt[c];
        int start = off[c] - n;             // off was advanced to run end
        float m0 = 0.0f, m1 = 0.0f;
        if (lact) {
            const unsigned* fp = feats + (size_t)start * npair + l;
            int p = 0;
            for (; p + 4 <= n; p += 4) {
                unsigned u0 = fp[(size_t)(p + 0) * npair];
                unsigned u1 = fp[(size_t)(p + 1) * npair];
                unsigned u2 = fp[(size_t)(p + 2) * npair];
                unsigned u3 = fp[(size_t)(p + 3) * npair];
                __half2 h0 = __builtin_bit_cast(__half2, u0);
                __half2 h1 = __builtin_bit_cast(__half2, u1);
                __half2 h2 = __builtin_bit_cast(__half2, u2);
                __half2 h3 = __builtin_bit_cast(__half2, u3);
                m0 = fmaxf(m0, fmaxf(fmaxf(__low2float(h0), __low2float(h1)),
                                     fmaxf(__low2float(h2), __low2float(h3))));
                m1 = fmaxf(m1, fmaxf(fmaxf(__high2float(h0), __high2float(h1)),
                                     fmaxf(__high2float(h2), __high2float(h3))));
            }
            for (; p < n; ++p) {
                __half2 h = __builtin_bit_cast(__half2, fp[(size_t)p * npair]);
                m0 = fmaxf(m0, __low2float(h));
                m1 = fmaxf(m1, __high2float(h));
            }
            tile[2 * l + 0][w * 16 + cc] = m0;
            tile[2 * l + 1][w * 16 + cc] = m1;
        }
    }
    __syncthreads();
    const int b = c0 >> 14;
    const int cxy = c0 & (HW - 1);
    const int nf = 8 * ccount;
#pragma unroll 1
    for (int k = 0; k < 2 * ccount; ++k) {
        int idx = k * 256 + tid;
        int f = idx >> 6, c = idx & 63;
        if (f < nf)
            out[((size_t)(b * 128 + cbegin * 8 + f)) * HW + cxy + c] = tile[f][c];
    }
}

// ---------------- B path: atomic fallback (run-merged) ----------------
#define DPPMAX(A, D, S) { \
    float _pv = __int_as_float(__builtin_amdgcn_update_dpp( \
        0, __float_as_int(A), 0x110 | (D), 0xF, 0xF, false)); \
    A = (S) ? fmaxf(A, _pv) : A; }

__global__ __launch_bounds__(256, 4)
void mlp_atomic_k(const float4* __restrict__ pts, const float* __restrict__ wf,
                  const int* __restrict__ sidx, const int* __restrict__ scell,
                  const int* __restrict__ nvp, float* __restrict__ bev, int layout)
{
    const unsigned* wu = (const unsigned*)wf;
    const int tid = threadIdx.x;
    const int slot = blockIdx.x * 256 + tid;
    const int nv = nvp[0];
    if ((slot & ~63) >= nv) return;
    const int lane = tid & 63;
    const int l15 = lane & 15;
    const bool live = slot < nv;
    const int cell = live ? scell[slot] : -1;
    const int pidx = live ? sidx[slot] : 0;
    float4 p = pts[pidx];

    int c1 = __shfl_up(cell, 1), c2 = __shfl_up(cell, 2);
    int c4 = __shfl_up(cell, 4), c8 = __shfl_up(cell, 8);
    bool s1 = (l15 >= 1) && (c1 == cell);
    bool s2 = (l15 >= 2) && (c2 == cell);
    bool s4 = (l15 >= 4) && (c4 == cell);
    bool s8 = (l15 >= 8) && (c8 == cell);
    int cn = __shfl_down(cell, 1);
    bool tail = (l15 == 15) || (cn != cell);

    unsigned h2p[64];
    mlp12(p, wf, wu, h2p);

    int* ob = (int*)bev;
    long base0;
    if (layout == 0) base0 = (long)cell * 128;
    else             base0 = (long)(cell >> 14) * (128 * HW) + (cell & (HW - 1));

#pragma unroll 1
    for (int ch = 0; ch < 16; ++ch) {
        float a[8];
        l3chunk(ch, wf, wu, h2p, a);
#pragma unroll
        for (int j = 0; j < 8; ++j) {
            a[j] = fmaxf(a[j], 0.0f);
            DPPMAX(a[j], 1, s1); DPPMAX(a[j], 2, s2);
            DPPMAX(a[j], 4, s4); DPPMAX(a[j], 8, s8);
        }
        if (tail && cell >= 0) {
            if (layout == 0) {
#pragma unroll
                for (int j = 0; j < 8; ++j)
                    atomicMax(ob + base0 + ch * 8 + j, __float_as_int(a[j]));
            } else {
#pragma unroll
                for (int j = 0; j < 8; ++j)
                    atomicMax(ob + base0 + (long)(ch * 8 + j) * HW, __float_as_int(a[j]));
            }
        }
    }
}

__global__ void transpose_bev_k(const float* __restrict__ bev, float* __restrict__ out)
{
    __shared__ float tile[32][129];
    const int tid = threadIdx.x;
    const int cell0 = blockIdx.x * 32;
#pragma unroll
    for (int k = 0; k < 16; ++k) {
        int idx = k * 256 + tid;
        int c = idx >> 7, f = idx & 127;
        tile[c][f] = bev[(size_t)(cell0 + c) * 128 + f];
    }
    __syncthreads();
    const int b = cell0 >> 14;
    const int cl0 = cell0 & (HW - 1);
#pragma unroll
    for (int k = 0; k < 16; ++k) {
        int idx = k * 256 + tid;
        int f = idx >> 5, c = idx & 31;
        out[(size_t)(b * 128 + f) * HW + cl0 + c] = tile[c][f];
    }
}

extern "C" void kernel_launch(void* const* d_in, const int* in_sizes, int n_in,
                              void* d_out, int out_size, void* d_ws, size_t ws_size,
                              hipStream_t stream)
{
    const float* points = (const float*)d_in[0];
    const float* W1 = (const float*)d_in[1];  const float* b1 = (const float*)d_in[2];
    const float* g1 = (const float*)d_in[3];  const float* be1 = (const float*)d_in[4];
    const float* m1 = (const float*)d_in[5];  const float* v1 = (const float*)d_in[6];
    const float* W2 = (const float*)d_in[7];  const float* b2 = (const float*)d_in[8];
    const float* g2 = (const float*)d_in[9];  const float* be2 = (const float*)d_in[10];
    const float* m2 = (const float*)d_in[11]; const float* v2 = (const float*)d_in[12];
    const float* W3 = (const float*)d_in[13]; const float* b3 = (const float*)d_in[14];
    const float* g3 = (const float*)d_in[15]; const float* be3 = (const float*)d_in[16];
    const float* m3 = (const float*)d_in[17]; const float* v3 = (const float*)d_in[18];

    float* wsf = (float*)d_ws;
    int*   wsi = (int*)d_ws;
    const size_t need_full = ((size_t)OFEATS + (size_t)NPTS * 64) * 4;  // ~129 MB
    const size_t need_half = ((size_t)OFEATS + (size_t)NPTS * 32) * 4;  // ~68 MB
    const size_t need_bev  = ((size_t)OBEV + BEV_ELEMS) * 4;            // ~40 MB

    fold_weights_k<<<51, 256, 0, stream>>>(
        W1, b1, g1, be1, m1, v1, W2, b2, g2, be2, m2, v2, W3, b3, g3, be3, m3, v3, wsf);

    // sort-by-cell (ws >= 6.4 MB established by round-2 run)
    hipMemsetAsync(wsi + OCNT, 0, 65536 * sizeof(int), stream);
    cells_hist_k<<<NPTS / 256, 256, 0, stream>>>(
        (const float4*)points, wsi + OCELLS, wsi + OCNT);
    scan_k<<<1, 1024, 0, stream>>>(wsi + OCNT, wsi + OOFF, wsi + ONV);
    scatter_idx_k<<<NPTS / 256, 256, 0, stream>>>(
        wsi + OCELLS, wsi + OOFF, wsi + OSIDX, wsi + OSCELL);

    if (ws_size >= need_full) {
        uint4* feats4 = (uint4*)(wsi + OFEATS);
        mlp_feats_k<<<NPTS / 256, 256, 0, stream>>>(
            (const float4*)points, wsf, wsi + OSIDX, wsi + ONV, feats4, 0, 16);
        reduce_k<<<BB * HW / 64, 256, 0, stream>>>(
            (const unsigned*)feats4, wsi + OOFF, wsi + OCNT, (float*)d_out, 0, 16);
    } else if (ws_size >= need_half) {
        uint4* feats4 = (uint4*)(wsi + OFEATS);
        for (int pass = 0; pass < 2; ++pass) {
            mlp_feats_k<<<NPTS / 256, 256, 0, stream>>>(
                (const float4*)points, wsf, wsi + OSIDX, wsi + ONV, feats4, pass * 8, 8);
            reduce_k<<<BB * HW / 64, 256, 0, stream>>>(
                (const unsigned*)feats4, wsi + OOFF, wsi + OCNT, (float*)d_out, pass * 8, 8);
        }
    } else if (ws_size >= need_bev) {
        float* bev = wsf + OBEV;
        hipMemsetAsync(bev, 0, (size_t)BEV_ELEMS * sizeof(float), stream);
        mlp_atomic_k<<<NPTS / 256, 256, 0, stream>>>(
            (const float4*)points, wsf, wsi + OSIDX, wsi + OSCELL, wsi + ONV, bev, 0);
        transpose_bev_k<<<HW * BB / 32, 256, 0, stream>>>(bev, (float*)d_out);
    } else {
        hipMemsetAsync(d_out, 0, (size_t)out_size * sizeof(float), stream);
        mlp_atomic_k<<<NPTS / 256, 256, 0, stream>>>(
            (const float4*)points, wsf, wsi + OSIDX, wsi + OSCELL, wsi + ONV,
            (float*)d_out, 1);
    }
}